// Round 6
// baseline (185.534 us; speedup 1.0000x reference)
//
#include <hip/hip_runtime.h>
#include <hip/hip_bf16.h>

#define Bn  2
#define Sn  2048
#define Hn  1024
#define NHn 16
#define DHn 64
#define Mn  (Bn * Sn)   // 4096 rows of X

typedef __attribute__((ext_vector_type(4)))  float    f32x4;
typedef __attribute__((ext_vector_type(16))) float    f32x16;
typedef __attribute__((ext_vector_type(8)))  _Float16 h8;
typedef __attribute__((ext_vector_type(4)))  _Float16 h4;
typedef __attribute__((ext_vector_type(2)))  __fp16   fp16x2;
typedef __attribute__((ext_vector_type(2)))  unsigned int u32x2;

union H2PK { fp16x2 v; unsigned int u; };
union U4H8 { unsigned int u[4]; h8 v; };

#define MFMA16F(a, b, c) __builtin_amdgcn_mfma_f32_16x16x32_f16(a, b, c, 0, 0, 0)
#define MFMA32F(a, b, c) __builtin_amdgcn_mfma_f32_32x32x16_f16(a, b, c, 0, 0, 0)

// score scale 0.125 (=1/sqrt(64)) pre-multiplied by log2(e), folded into Qh
#define SCFULL 0.18033688011112042f
#define L2E    1.44269504088896340736f

// async global->LDS: LDS dest = wave-uniform base + lane*16 (m104)
__device__ __forceinline__ void glds16(const void* g, void* l) {
    __builtin_amdgcn_global_load_lds(
        (const __attribute__((address_space(1))) unsigned int*)g,
        (__attribute__((address_space(3))) unsigned int*)l, 16, 0, 0);
}

// ---------------------------------------------------------------------------
// Fused prepass: blocks [0,4096) convert X fp32->fp16; blocks [4096,4864)
// transpose+convert one 64x64 tile of one W matrix.
// ---------------------------------------------------------------------------
__global__ __launch_bounds__(256) void prep(
    const float* __restrict__ X, const float* __restrict__ W0,
    const float* __restrict__ W1, const float* __restrict__ W2,
    _Float16* __restrict__ Xh, _Float16* __restrict__ WT)
{
    const int bid = blockIdx.x;
    const int tid = threadIdx.x;
    __shared__ float Ws[64][65];

    if (bid < 4096) {
        const int i = bid * 256 + tid;   // over Mn*Hn/4 float4s
        float4 x = ((const float4*)X)[i];
        h4 o;
        o[0] = (_Float16)x.x; o[1] = (_Float16)x.y;
        o[2] = (_Float16)x.z; o[3] = (_Float16)x.w;
        *(h4*)&Xh[(size_t)i * 4] = o;
        return;
    }

    const int wb = bid - 4096;              // 0..767
    const int which = wb >> 8;              // 0..2
    const int rem = wb & 255;
    const int k0 = ((rem >> 4) & 15) * 64;
    const int n0 = (rem & 15) * 64;
    const float* W = (which == 0) ? W0 : (which == 1 ? W1 : W2);
    _Float16* O = WT + (size_t)which * Hn * Hn;

#pragma unroll
    for (int it = 0; it < 4; ++it) {
        const int idx = tid + 256 * it;
        const int row = idx >> 4, c4 = (idx & 15) * 4;
        float4 w = *(const float4*)&W[(size_t)(k0 + row) * Hn + n0 + c4];
        Ws[row][c4 + 0] = w.x; Ws[row][c4 + 1] = w.y;
        Ws[row][c4 + 2] = w.z; Ws[row][c4 + 3] = w.w;
    }
    __syncthreads();
#pragma unroll
    for (int it = 0; it < 16; ++it) {
        const int e = tid + 256 * it;
        const int k = e & 63, n = e >> 6;
        O[(size_t)(n0 + n) * Hn + k0 + k] = (_Float16)Ws[k][n];
    }
}

// ---------------------------------------------------------------------------
// QKV projection, fp16 MFMA, 128x128 tile, BK=32, 4 waves (2x2).
// Round-6: T3-minimum pipeline — double-buffered Ah/Bh, stage(kt+1) issued
// BEFORE compute(kt), counted s_waitcnt vmcnt(4) (never 0 mid-loop), raw
// s_barrier x2/step (no __syncthreads vmcnt(0) drain). Race-safe: barrier2 at
// end of body ensures all waves done reading buf[(kt+1)&1] (last read in iter
// kt-1) before any wave's stage(kt+1) overwrites it.
// which==0 (Q): epilogue multiplies by SCFULL (score scale folded into Q).
// ---------------------------------------------------------------------------
__global__ __launch_bounds__(256) void qkv_mfma(
    const _Float16* __restrict__ Xh, const _Float16* __restrict__ WTA,
    const float* __restrict__ b0, const float* __restrict__ b1,
    const float* __restrict__ b2,
    _Float16* __restrict__ Qh, _Float16* __restrict__ Kh,
    _Float16* __restrict__ VTh)
{
    const int which = blockIdx.z;
    const _Float16* WT = WTA + (size_t)which * Hn * Hn;
    const float* bias = (which == 0) ? b0 : (which == 1 ? b1 : b2);
    _Float16* Dst = (which == 0) ? Qh : (which == 1 ? Kh : VTh);

    const int m0 = blockIdx.x * 128;
    const int n0 = blockIdx.y * 128;
    const int tid  = threadIdx.x;
    const int wid  = tid >> 6;
    const int lane = tid & 63;
    const int l16  = lane & 15;
    const int quad = lane >> 4;
    const int wm = wid >> 1, wn = wid & 1;

    __shared__ _Float16 Ah[2][128 * 32], Bh[2][128 * 32];   // 8 KB each x4

    f32x4 acc[4][4];
#pragma unroll
    for (int i = 0; i < 4; ++i)
#pragma unroll
        for (int j = 0; j < 4; ++j) acc[i][j] = (f32x4){0.f, 0.f, 0.f, 0.f};

    auto stage = [&](int kt, int bb) {
        const int k0 = kt * 32;
#pragma unroll
        for (int c = 0; c < 2; ++c) {
            const int idx = (wid * 2 + c) * 64 + lane;   // linear 16B chunk
            const int row = idx >> 2;
            const int cg  = (idx & 3) ^ (row & 3);       // swizzled global chunk
            glds16(&Xh[(size_t)(m0 + row) * Hn + k0 + cg * 8],
                   &Ah[bb][(wid * 2 + c) * 512]);
            glds16(&WT[(size_t)(n0 + row) * Hn + k0 + cg * 8],
                   &Bh[bb][(wid * 2 + c) * 512]);
        }
    };

    stage(0, 0);

    for (int kt = 0; kt < Hn / 32; ++kt) {
        if (kt + 1 < Hn / 32) {
            stage(kt + 1, (kt + 1) & 1);
            asm volatile("s_waitcnt vmcnt(4)" ::: "memory");  // tile kt landed
        } else {
            asm volatile("s_waitcnt vmcnt(0)" ::: "memory");
        }
        __builtin_amdgcn_s_barrier();
        asm volatile("" ::: "memory");

        const int bb = kt & 1;
        h8 xa[4], wb[4];
#pragma unroll
        for (int t = 0; t < 4; ++t) {
            const int ar = wm * 64 + t * 16 + l16;
            const int br = wn * 64 + t * 16 + l16;
            xa[t] = *(const h8*)&Ah[bb][ar * 32 + ((quad ^ (ar & 3)) * 8)];
            wb[t] = *(const h8*)&Bh[bb][br * 32 + ((quad ^ (br & 3)) * 8)];
        }
        if (which < 2) {
#pragma unroll
            for (int i = 0; i < 4; ++i)
#pragma unroll
                for (int j = 0; j < 4; ++j)
                    acc[i][j] = MFMA16F(xa[i], wb[j], acc[i][j]);
        } else {
#pragma unroll
            for (int i = 0; i < 4; ++i)
#pragma unroll
                for (int j = 0; j < 4; ++j)
                    acc[i][j] = MFMA16F(wb[i], xa[j], acc[i][j]);
        }
        __builtin_amdgcn_s_barrier();
        asm volatile("" ::: "memory");
    }

    const float oscale = (which == 0) ? SCFULL : 1.0f;
    if (which < 2) {
        // D[m=quad*4+r][n=l16] -> [bh][s][d]
#pragma unroll
        for (int j = 0; j < 4; ++j) {
            const int n = n0 + wn * 64 + j * 16 + l16;
            const float bv = bias[n];
            const int hh = n >> 6, dd = n & 63;
#pragma unroll
            for (int i = 0; i < 4; ++i) {
                const int mb = m0 + wm * 64 + i * 16 + quad * 4;
#pragma unroll
                for (int r = 0; r < 4; ++r) {
                    const int m = mb + r;
                    const int b = m >> 11, s = m & (Sn - 1);
                    Dst[(((size_t)b * NHn + hh) * Sn + s) * DHn + dd] =
                        (_Float16)((acc[i][j][r] + bv) * oscale);
                }
            }
        }
    } else {
        // swapped: D rows = n-dim, cols = m-dim -> [bh][d][s]
#pragma unroll
        for (int i = 0; i < 4; ++i) {
#pragma unroll
            for (int r = 0; r < 4; ++r) {
                const int n = n0 + wn * 64 + i * 16 + quad * 4 + r;
                const float bv = bias[n];
                const int hh = n >> 6, dd = n & 63;
#pragma unroll
                for (int j = 0; j < 4; ++j) {
                    const int m = m0 + wm * 64 + j * 16 + l16;
                    const int b = m >> 11, s = m & (Sn - 1);
                    Dst[(((size_t)b * NHn + hh) * DHn + dd) * Sn + s] =
                        (_Float16)(acc[i][j][r] + bv);
                }
            }
        }
    }
}

// ---------------------------------------------------------------------------
// Flash attention (T15 pipeline, round-5 structure).
// Round-6: score scale folded into Qh (qkv); mask*log2e folded into the QK^T
// accumulator INIT (C/D row = e+8g+4hi matches the mv float4 exactly), so
// sm_pv's exp2 takes the MFMA output directly: -32 v_fmac/iter, mask ds_reads
// move from sm_pv to qkt (same LDS count, earlier on the dep chain).
// ---------------------------------------------------------------------------
__global__ __launch_bounds__(256, 2) void attn(
    const _Float16* __restrict__ Qh, const _Float16* __restrict__ Kh,
    const _Float16* __restrict__ VTh, const float* __restrict__ mask,
    float* __restrict__ Out)
{
    // --- XCD-grouping remap: 512 blocks, 8 XCDs, 4 bh per XCD ---
    const int flat = blockIdx.x + 16 * blockIdx.y + 256 * blockIdx.z;
    const int bh   = ((flat & 7) << 2) | ((flat >> 3) & 3);  // 0..31
    const int qb   = flat >> 5;                              // 0..15
    const int b = bh >> 4, h = bh & 15;

    const int tid  = threadIdx.x;
    const int wid  = tid >> 6;
    const int lane = tid & 63;
    const int l32  = lane & 31;
    const int hi   = lane >> 5;

    __shared__ __align__(16) _Float16 Kb[4][4096];  // [key][dim], swizzled
    __shared__ __align__(16) _Float16 Vb[4][4096];  // [dim][key], swizzled
    __shared__ float4 Ml4[Sn / 4];                  // full mask row * log2(e)
    const float* Ml = (const float*)Ml4;

    const int q0 = qb * 128 + wid * 32;

    // mask + Q loads first, then drain vmcnt so only stage loads remain
    const float4* mg = (const float4*)(mask + (size_t)b * Sn);
    float4 m0v = mg[tid], m1v = mg[tid + 256];

    const size_t qbase = ((size_t)bh * Sn + q0 + l32) * DHn;
    h8 qf[4];   // B-frag: B[k=dim][n=q=l32]
#pragma unroll
    for (int kd = 0; kd < 4; ++kd)
        qf[kd] = *(const h8*)&Qh[qbase + kd * 16 + hi * 8];

    asm volatile("s_waitcnt vmcnt(0)" ::: "memory");

    {
        float4 a0 = {m0v.x * L2E, m0v.y * L2E, m0v.z * L2E, m0v.w * L2E};
        float4 a1 = {m1v.x * L2E, m1v.y * L2E, m1v.z * L2E, m1v.w * L2E};
        Ml4[tid] = a0;
        Ml4[tid + 256] = a1;
    }

    const _Float16* Kg = Kh  + (size_t)bh * Sn * DHn;   // [key][dim]
    const _Float16* Vg = VTh + (size_t)bh * DHn * Sn;   // [dim][key]

    // stage one 64-key tile (4 glds16 per thread: K0,V0,K1,V1)
    auto stage = [&](int kt, int buf) {
        const int koff = kt * 64;
#pragma unroll
        for (int c = 0; c < 2; ++c) {
            const int idx = (wid * 2 + c) * 64 + lane;
            const int row = idx >> 3;
            const int cg  = (idx & 7) ^ (row & 7);
            glds16(&Kg[(size_t)(koff + row) * DHn + cg * 8],
                   &Kb[buf][(wid * 2 + c) * 512]);
            glds16(&Vg[(size_t)row * Sn + koff + cg * 8],
                   &Vb[buf][(wid * 2 + c) * 512]);
        }
    };

    stage(0, 0);
    stage(1, 1);

    f32x16 sA[2], sB[2], o[2], acc_l;
#pragma unroll
    for (int dt = 0; dt < 2; ++dt) o[dt] = (f32x16)(0.f);
    acc_l = (f32x16)(0.f);

    h8 ones;
#pragma unroll
    for (int j = 0; j < 8; ++j) ones[j] = (_Float16)1.0f;

    // D = K.Q^T for 64-key tile `ktile` -> s[2]; C init = mask*log2e
    auto qkt = [&](f32x16 (&s)[2], int buf, int ktile) {
        __builtin_amdgcn_s_setprio(1);
#pragma unroll
        for (int t = 0; t < 2; ++t) {
            f32x16 c;
#pragma unroll
            for (int g = 0; g < 4; ++g) {
                float4 mv = *(const float4*)&Ml[ktile * 64 + t * 32 + hi * 4 + g * 8];
                c[g * 4 + 0] = mv.x; c[g * 4 + 1] = mv.y;
                c[g * 4 + 2] = mv.z; c[g * 4 + 3] = mv.w;
            }
#pragma unroll
            for (int kd = 0; kd < 4; ++kd) {
                const int row = t * 32 + l32;   // A-frag: A[m=key=row][k=dim]
                h8 kf = *(const h8*)&Kb[buf][row * 64 +
                                             (((kd * 2 + hi) ^ (row & 7)) * 8)];
                c = MFMA32F(kf, qf[kd], c);
            }
            s[t] = c;
        }
        __builtin_amdgcn_s_setprio(0);
    };

    // softmax from s (already scaled+masked), permlane exchange + PV + l-MFMA
    auto sm_pv = [&](f32x16 (&s)[2], int buf) {
        unsigned int pk[2][4][2];
#pragma unroll
        for (int t = 0; t < 2; ++t) {
#pragma unroll
            for (int g = 0; g < 4; ++g) {
                const float p0 = __builtin_amdgcn_exp2f(s[t][g * 4 + 0]);
                const float p1 = __builtin_amdgcn_exp2f(s[t][g * 4 + 1]);
                const float p2 = __builtin_amdgcn_exp2f(s[t][g * 4 + 2]);
                const float p3 = __builtin_amdgcn_exp2f(s[t][g * 4 + 3]);
                H2PK u0, u1;
                u0.v = __builtin_amdgcn_cvt_pkrtz(p0, p1);
                u1.v = __builtin_amdgcn_cvt_pkrtz(p2, p3);
                pk[t][g][0] = u0.u;
                pk[t][g][1] = u1.u;
            }
        }

        __builtin_amdgcn_s_setprio(1);
#pragma unroll
        for (int ks = 0; ks < 4; ++ks) {
            const int t = ks >> 1, ge = (ks & 1) * 2;   // ge feeds dest hi=0
            u32x2 rA = __builtin_amdgcn_permlane32_swap(
                pk[t][ge][0], pk[t][ge + 1][0], false, false);
            u32x2 rB = __builtin_amdgcn_permlane32_swap(
                pk[t][ge][1], pk[t][ge + 1][1], false, false);
            U4H8 w;
            w.u[0] = rA[0]; w.u[1] = rB[0]; w.u[2] = rA[1]; w.u[3] = rB[1];
            acc_l = MFMA32F(w.v, ones, acc_l);   // row-sum of P -> l
#pragma unroll
            for (int dt = 0; dt < 2; ++dt) {
                const int row = dt * 32 + l32;   // B-frag: B[k=key][n=dim=row]
                h8 vf = *(const h8*)&Vb[buf][row * 64 +
                                             (((ks * 2 + hi) ^ (row & 7)) * 8)];
                o[dt] = MFMA32F(w.v, vf, o[dt]);
            }
        }
        __builtin_amdgcn_s_setprio(0);
    };

    // prologue: tile0 resident -> scores(0) into sA
    asm volatile("s_waitcnt vmcnt(4) lgkmcnt(0)" ::: "memory");
    __builtin_amdgcn_s_barrier();
    qkt(sA, 0, 0);

    auto iter = [&](int kt, f32x16 (&scur)[2], f32x16 (&snxt)[2]) {
        stage(kt + 2, (kt + 2) & 3);
        asm volatile("s_waitcnt vmcnt(4)" ::: "memory");  // tile kt+1 landed
        __builtin_amdgcn_s_barrier();
        qkt(snxt, (kt + 1) & 3, kt + 1);   // MFMA, overlaps softmax below
        sm_pv(scur, kt & 3);               // VALU + PV MFMA
    };

    for (int kt = 0; kt < 30; kt += 2) {
        iter(kt,     sA, sB);
        iter(kt + 1, sB, sA);
    }
    // kt = 30: no more staging; tile 31 needs full drain
    asm volatile("s_waitcnt vmcnt(0)" ::: "memory");
    __builtin_amdgcn_s_barrier();
    qkt(sB, 31 & 3, 31);
    sm_pv(sA, 30 & 3);
    // kt = 31
    sm_pv(sB, 31 & 3);

    // ---- final: per-lane l (same C/D row mapping as o), normalize, store ----
#pragma unroll
    for (int g2 = 0; g2 < 4; ++g2) {
#pragma unroll
        for (int e = 0; e < 4; ++e) {
            const int r = g2 * 4 + e;
            const int q = q0 + 4 * hi + 8 * g2 + e;   // C/D row formula
            const size_t ob = ((size_t)b * Sn + q) * Hn + h * DHn;
            const float sc = 1.0f / acc_l[r];
#pragma unroll
            for (int dt = 0; dt < 2; ++dt)
                Out[ob + dt * 32 + l32] = o[dt][r] * sc;
        }
    }
}

extern "C" void kernel_launch(void* const* d_in, const int* in_sizes, int n_in,
                              void* d_out, int out_size, void* d_ws, size_t ws_size,
                              hipStream_t stream) {
    const float* X    = (const float*)d_in[0];
    const float* mask = (const float*)d_in[1];
    const float* Wq   = (const float*)d_in[2];
    const float* bq   = (const float*)d_in[3];
    const float* Wk   = (const float*)d_in[4];
    const float* bk   = (const float*)d_in[5];
    const float* Wv   = (const float*)d_in[6];
    const float* bv   = (const float*)d_in[7];
    float* out = (float*)d_out;

    const size_t NE = (size_t)Mn * Hn;         // 4M elements
    _Float16* Xh  = (_Float16*)d_ws;           // 8 MB
    _Float16* WT  = Xh + NE;                   // 3 x 2 MB
    _Float16* Qh  = WT + (size_t)3 * Hn * Hn;  // 8 MB
    _Float16* Kh  = Qh + NE;                   // 8 MB
    _Float16* VTh = Kh + NE;                   // 8 MB (total 38 MB)

    prep<<<dim3(4096 + 768), dim3(256), 0, stream>>>(X, Wq, Wk, Wv, Xh, WT);

    dim3 g1(Mn / 128, Hn / 128, 3), b1(256);
    qkv_mfma<<<g1, b1, 0, stream>>>(Xh, WT, bq, bk, bv, Qh, Kh, VTh);

    dim3 g2(Sn / 128, NHn, Bn), b2(256);
    attn<<<g2, b2, 0, stream>>>(Qh, Kh, VTh, mask, out);
}

// Round 7
// 168.193 us; speedup vs baseline: 1.1031x; 1.1031x over previous
//
#include <hip/hip_runtime.h>
#include <hip/hip_bf16.h>

#define Bn  2
#define Sn  2048
#define Hn  1024
#define NHn 16
#define DHn 64
#define Mn  (Bn * Sn)   // 4096 rows of X

typedef __attribute__((ext_vector_type(4)))  float    f32x4;
typedef __attribute__((ext_vector_type(16))) float    f32x16;
typedef __attribute__((ext_vector_type(8)))  _Float16 h8;
typedef __attribute__((ext_vector_type(4)))  _Float16 h4;
typedef __attribute__((ext_vector_type(2)))  __fp16   fp16x2;
typedef __attribute__((ext_vector_type(2)))  unsigned int u32x2;

union H2PK { fp16x2 v; unsigned int u; };
union U4H8 { unsigned int u[4]; h8 v; };

#define MFMA16F(a, b, c) __builtin_amdgcn_mfma_f32_16x16x32_f16(a, b, c, 0, 0, 0)
#define MFMA32F(a, b, c) __builtin_amdgcn_mfma_f32_32x32x16_f16(a, b, c, 0, 0, 0)

// score scale 0.125 (=1/sqrt(64)) pre-multiplied by log2(e), folded into Qh
#define SCFULL 0.18033688011112042f
#define L2E    1.44269504088896340736f

// async global->LDS: LDS dest = wave-uniform base + lane*16 (m104)
__device__ __forceinline__ void glds16(const void* g, void* l) {
    __builtin_amdgcn_global_load_lds(
        (const __attribute__((address_space(1))) unsigned int*)g,
        (__attribute__((address_space(3))) unsigned int*)l, 16, 0, 0);
}

// ---------------------------------------------------------------------------
// Fused prepass: blocks [0,4096) convert X fp32->fp16; blocks [4096,4864)
// transpose+convert one 64x64 tile of one W matrix.
// ---------------------------------------------------------------------------
__global__ __launch_bounds__(256) void prep(
    const float* __restrict__ X, const float* __restrict__ W0,
    const float* __restrict__ W1, const float* __restrict__ W2,
    _Float16* __restrict__ Xh, _Float16* __restrict__ WT)
{
    const int bid = blockIdx.x;
    const int tid = threadIdx.x;
    __shared__ float Ws[64][65];

    if (bid < 4096) {
        const int i = bid * 256 + tid;   // over Mn*Hn/4 float4s
        float4 x = ((const float4*)X)[i];
        h4 o;
        o[0] = (_Float16)x.x; o[1] = (_Float16)x.y;
        o[2] = (_Float16)x.z; o[3] = (_Float16)x.w;
        *(h4*)&Xh[(size_t)i * 4] = o;
        return;
    }

    const int wb = bid - 4096;              // 0..767
    const int which = wb >> 8;              // 0..2
    const int rem = wb & 255;
    const int k0 = ((rem >> 4) & 15) * 64;
    const int n0 = (rem & 15) * 64;
    const float* W = (which == 0) ? W0 : (which == 1 ? W1 : W2);
    _Float16* O = WT + (size_t)which * Hn * Hn;

#pragma unroll
    for (int it = 0; it < 4; ++it) {
        const int idx = tid + 256 * it;
        const int row = idx >> 4, c4 = (idx & 15) * 4;
        float4 w = *(const float4*)&W[(size_t)(k0 + row) * Hn + n0 + c4];
        Ws[row][c4 + 0] = w.x; Ws[row][c4 + 1] = w.y;
        Ws[row][c4 + 2] = w.z; Ws[row][c4 + 3] = w.w;
    }
    __syncthreads();
#pragma unroll
    for (int it = 0; it < 16; ++it) {
        const int e = tid + 256 * it;
        const int k = e & 63, n = e >> 6;
        O[(size_t)(n0 + n) * Hn + k0 + k] = (_Float16)Ws[k][n];
    }
}

// ---------------------------------------------------------------------------
// QKV projection, fp16 MFMA, 128x128 tile, 4 waves (2x2).
// Round-7: round-6's explicit dbuf pipeline REGRESSED (61.5us, MfmaUtil 16%,
// in-flight glds writes contend with ds_reads) -> revert to the proven
// m97-style drain structure (sync; stage; sync(drain); compute) but with
// BK=64: halves the number of exposed vmcnt(0) drains (16 steps vs 32).
// LDS 2x16KB = 32KB -> still 3 blocks/CU. Swizzle: rows are 128B = 8 chunks,
// chunk c stored at c^(row&7) (applied on the global address side).
// which==0 (Q): epilogue multiplies by SCFULL (score scale folded into Q).
// ---------------------------------------------------------------------------
__global__ __launch_bounds__(256) void qkv_mfma(
    const _Float16* __restrict__ Xh, const _Float16* __restrict__ WTA,
    const float* __restrict__ b0, const float* __restrict__ b1,
    const float* __restrict__ b2,
    _Float16* __restrict__ Qh, _Float16* __restrict__ Kh,
    _Float16* __restrict__ VTh)
{
    const int which = blockIdx.z;
    const _Float16* WT = WTA + (size_t)which * Hn * Hn;
    const float* bias = (which == 0) ? b0 : (which == 1 ? b1 : b2);
    _Float16* Dst = (which == 0) ? Qh : (which == 1 ? Kh : VTh);

    const int m0 = blockIdx.x * 128;
    const int n0 = blockIdx.y * 128;
    const int tid  = threadIdx.x;
    const int wid  = tid >> 6;
    const int lane = tid & 63;
    const int l16  = lane & 15;
    const int quad = lane >> 4;
    const int wm = wid >> 1, wn = wid & 1;

    __shared__ _Float16 Ah[128 * 64], Bh[128 * 64];   // 16 KB each

    f32x4 acc[4][4];
#pragma unroll
    for (int i = 0; i < 4; ++i)
#pragma unroll
        for (int j = 0; j < 4; ++j) acc[i][j] = (f32x4){0.f, 0.f, 0.f, 0.f};

    for (int kt = 0; kt < Hn / 64; ++kt) {   // 16 K-steps of 64
        const int k0 = kt * 64;
        __syncthreads();   // compute(kt-1) reads done before overwrite
#pragma unroll
        for (int c = 0; c < 4; ++c) {
            const int idx = (wid * 4 + c) * 64 + lane;   // 16B chunk id, 0..1023
            const int row = idx >> 3;                    // 0..127
            const int cg  = (idx & 7) ^ (row & 7);       // swizzled global chunk
            glds16(&Xh[(size_t)(m0 + row) * Hn + k0 + cg * 8],
                   &Ah[(wid * 4 + c) * 512]);
            glds16(&WT[(size_t)(n0 + row) * Hn + k0 + cg * 8],
                   &Bh[(wid * 4 + c) * 512]);
        }
        __syncthreads();   // drains vmcnt(0): tile kt fully in LDS

#pragma unroll
        for (int kk = 0; kk < 2; ++kk) {
            h8 xa[4], wb[4];
#pragma unroll
            for (int t = 0; t < 4; ++t) {
                const int ar = wm * 64 + t * 16 + l16;
                const int br = wn * 64 + t * 16 + l16;
                // global chunk kk*4+quad (k = kk*32 + quad*8 + j), de-swizzled
                xa[t] = *(const h8*)&Ah[ar * 64 + (((kk * 4 + quad) ^ (ar & 7)) * 8)];
                wb[t] = *(const h8*)&Bh[br * 64 + (((kk * 4 + quad) ^ (br & 7)) * 8)];
            }
            if (which < 2) {
#pragma unroll
                for (int i = 0; i < 4; ++i)
#pragma unroll
                    for (int j = 0; j < 4; ++j)
                        acc[i][j] = MFMA16F(xa[i], wb[j], acc[i][j]);
            } else {
#pragma unroll
                for (int i = 0; i < 4; ++i)
#pragma unroll
                    for (int j = 0; j < 4; ++j)
                        acc[i][j] = MFMA16F(wb[i], xa[j], acc[i][j]);
            }
        }
    }

    const float oscale = (which == 0) ? SCFULL : 1.0f;
    if (which < 2) {
        // D[m=quad*4+r][n=l16] -> [bh][s][d]
#pragma unroll
        for (int j = 0; j < 4; ++j) {
            const int n = n0 + wn * 64 + j * 16 + l16;
            const float bv = bias[n];
            const int hh = n >> 6, dd = n & 63;
#pragma unroll
            for (int i = 0; i < 4; ++i) {
                const int mb = m0 + wm * 64 + i * 16 + quad * 4;
#pragma unroll
                for (int r = 0; r < 4; ++r) {
                    const int m = mb + r;
                    const int b = m >> 11, s = m & (Sn - 1);
                    Dst[(((size_t)b * NHn + hh) * Sn + s) * DHn + dd] =
                        (_Float16)((acc[i][j][r] + bv) * oscale);
                }
            }
        }
    } else {
        // swapped: D rows = n-dim, cols = m-dim -> [bh][d][s]
#pragma unroll
        for (int i = 0; i < 4; ++i) {
#pragma unroll
            for (int r = 0; r < 4; ++r) {
                const int n = n0 + wn * 64 + i * 16 + quad * 4 + r;
                const float bv = bias[n];
                const int hh = n >> 6, dd = n & 63;
#pragma unroll
                for (int j = 0; j < 4; ++j) {
                    const int m = m0 + wm * 64 + j * 16 + l16;
                    const int b = m >> 11, s = m & (Sn - 1);
                    Dst[(((size_t)b * NHn + hh) * DHn + dd) * Sn + s] =
                        (_Float16)(acc[i][j][r] + bv);
                }
            }
        }
    }
}

// ---------------------------------------------------------------------------
// Flash attention (T15 pipeline + mask-as-C-init). UNCHANGED from round 6
// so this round's delta attributes entirely to qkv.
// ---------------------------------------------------------------------------
__global__ __launch_bounds__(256, 2) void attn(
    const _Float16* __restrict__ Qh, const _Float16* __restrict__ Kh,
    const _Float16* __restrict__ VTh, const float* __restrict__ mask,
    float* __restrict__ Out)
{
    // --- XCD-grouping remap: 512 blocks, 8 XCDs, 4 bh per XCD ---
    const int flat = blockIdx.x + 16 * blockIdx.y + 256 * blockIdx.z;
    const int bh   = ((flat & 7) << 2) | ((flat >> 3) & 3);  // 0..31
    const int qb   = flat >> 5;                              // 0..15
    const int b = bh >> 4, h = bh & 15;

    const int tid  = threadIdx.x;
    const int wid  = tid >> 6;
    const int lane = tid & 63;
    const int l32  = lane & 31;
    const int hi   = lane >> 5;

    __shared__ __align__(16) _Float16 Kb[4][4096];  // [key][dim], swizzled
    __shared__ __align__(16) _Float16 Vb[4][4096];  // [dim][key], swizzled
    __shared__ float4 Ml4[Sn / 4];                  // full mask row * log2(e)
    const float* Ml = (const float*)Ml4;

    const int q0 = qb * 128 + wid * 32;

    // mask + Q loads first, then drain vmcnt so only stage loads remain
    const float4* mg = (const float4*)(mask + (size_t)b * Sn);
    float4 m0v = mg[tid], m1v = mg[tid + 256];

    const size_t qbase = ((size_t)bh * Sn + q0 + l32) * DHn;
    h8 qf[4];   // B-frag: B[k=dim][n=q=l32]
#pragma unroll
    for (int kd = 0; kd < 4; ++kd)
        qf[kd] = *(const h8*)&Qh[qbase + kd * 16 + hi * 8];

    asm volatile("s_waitcnt vmcnt(0)" ::: "memory");

    {
        float4 a0 = {m0v.x * L2E, m0v.y * L2E, m0v.z * L2E, m0v.w * L2E};
        float4 a1 = {m1v.x * L2E, m1v.y * L2E, m1v.z * L2E, m1v.w * L2E};
        Ml4[tid] = a0;
        Ml4[tid + 256] = a1;
    }

    const _Float16* Kg = Kh  + (size_t)bh * Sn * DHn;   // [key][dim]
    const _Float16* Vg = VTh + (size_t)bh * DHn * Sn;   // [dim][key]

    // stage one 64-key tile (4 glds16 per thread: K0,V0,K1,V1)
    auto stage = [&](int kt, int buf) {
        const int koff = kt * 64;
#pragma unroll
        for (int c = 0; c < 2; ++c) {
            const int idx = (wid * 2 + c) * 64 + lane;
            const int row = idx >> 3;
            const int cg  = (idx & 7) ^ (row & 7);
            glds16(&Kg[(size_t)(koff + row) * DHn + cg * 8],
                   &Kb[buf][(wid * 2 + c) * 512]);
            glds16(&Vg[(size_t)row * Sn + koff + cg * 8],
                   &Vb[buf][(wid * 2 + c) * 512]);
        }
    };

    stage(0, 0);
    stage(1, 1);

    f32x16 sA[2], sB[2], o[2], acc_l;
#pragma unroll
    for (int dt = 0; dt < 2; ++dt) o[dt] = (f32x16)(0.f);
    acc_l = (f32x16)(0.f);

    h8 ones;
#pragma unroll
    for (int j = 0; j < 8; ++j) ones[j] = (_Float16)1.0f;

    // D = K.Q^T for 64-key tile `ktile` -> s[2]; C init = mask*log2e
    auto qkt = [&](f32x16 (&s)[2], int buf, int ktile) {
        __builtin_amdgcn_s_setprio(1);
#pragma unroll
        for (int t = 0; t < 2; ++t) {
            f32x16 c;
#pragma unroll
            for (int g = 0; g < 4; ++g) {
                float4 mv = *(const float4*)&Ml[ktile * 64 + t * 32 + hi * 4 + g * 8];
                c[g * 4 + 0] = mv.x; c[g * 4 + 1] = mv.y;
                c[g * 4 + 2] = mv.z; c[g * 4 + 3] = mv.w;
            }
#pragma unroll
            for (int kd = 0; kd < 4; ++kd) {
                const int row = t * 32 + l32;   // A-frag: A[m=key=row][k=dim]
                h8 kf = *(const h8*)&Kb[buf][row * 64 +
                                             (((kd * 2 + hi) ^ (row & 7)) * 8)];
                c = MFMA32F(kf, qf[kd], c);
            }
            s[t] = c;
        }
        __builtin_amdgcn_s_setprio(0);
    };

    // softmax from s (already scaled+masked), permlane exchange + PV + l-MFMA
    auto sm_pv = [&](f32x16 (&s)[2], int buf) {
        unsigned int pk[2][4][2];
#pragma unroll
        for (int t = 0; t < 2; ++t) {
#pragma unroll
            for (int g = 0; g < 4; ++g) {
                const float p0 = __builtin_amdgcn_exp2f(s[t][g * 4 + 0]);
                const float p1 = __builtin_amdgcn_exp2f(s[t][g * 4 + 1]);
                const float p2 = __builtin_amdgcn_exp2f(s[t][g * 4 + 2]);
                const float p3 = __builtin_amdgcn_exp2f(s[t][g * 4 + 3]);
                H2PK u0, u1;
                u0.v = __builtin_amdgcn_cvt_pkrtz(p0, p1);
                u1.v = __builtin_amdgcn_cvt_pkrtz(p2, p3);
                pk[t][g][0] = u0.u;
                pk[t][g][1] = u1.u;
            }
        }

        __builtin_amdgcn_s_setprio(1);
#pragma unroll
        for (int ks = 0; ks < 4; ++ks) {
            const int t = ks >> 1, ge = (ks & 1) * 2;   // ge feeds dest hi=0
            u32x2 rA = __builtin_amdgcn_permlane32_swap(
                pk[t][ge][0], pk[t][ge + 1][0], false, false);
            u32x2 rB = __builtin_amdgcn_permlane32_swap(
                pk[t][ge][1], pk[t][ge + 1][1], false, false);
            U4H8 w;
            w.u[0] = rA[0]; w.u[1] = rB[0]; w.u[2] = rA[1]; w.u[3] = rB[1];
            acc_l = MFMA32F(w.v, ones, acc_l);   // row-sum of P -> l
#pragma unroll
            for (int dt = 0; dt < 2; ++dt) {
                const int row = dt * 32 + l32;   // B-frag: B[k=key][n=dim=row]
                h8 vf = *(const h8*)&Vb[buf][row * 64 +
                                             (((ks * 2 + hi) ^ (row & 7)) * 8)];
                o[dt] = MFMA32F(w.v, vf, o[dt]);
            }
        }
        __builtin_amdgcn_s_setprio(0);
    };

    // prologue: tile0 resident -> scores(0) into sA
    asm volatile("s_waitcnt vmcnt(4) lgkmcnt(0)" ::: "memory");
    __builtin_amdgcn_s_barrier();
    qkt(sA, 0, 0);

    auto iter = [&](int kt, f32x16 (&scur)[2], f32x16 (&snxt)[2]) {
        stage(kt + 2, (kt + 2) & 3);
        asm volatile("s_waitcnt vmcnt(4)" ::: "memory");  // tile kt+1 landed
        __builtin_amdgcn_s_barrier();
        qkt(snxt, (kt + 1) & 3, kt + 1);   // MFMA, overlaps softmax below
        sm_pv(scur, kt & 3);               // VALU + PV MFMA
    };

    for (int kt = 0; kt < 30; kt += 2) {
        iter(kt,     sA, sB);
        iter(kt + 1, sB, sA);
    }
    // kt = 30: no more staging; tile 31 needs full drain
    asm volatile("s_waitcnt vmcnt(0)" ::: "memory");
    __builtin_amdgcn_s_barrier();
    qkt(sB, 31 & 3, 31);
    sm_pv(sA, 30 & 3);
    // kt = 31
    sm_pv(sB, 31 & 3);

    // ---- final: per-lane l (same C/D row mapping as o), normalize, store ----
#pragma unroll
    for (int g2 = 0; g2 < 4; ++g2) {
#pragma unroll
        for (int e = 0; e < 4; ++e) {
            const int r = g2 * 4 + e;
            const int q = q0 + 4 * hi + 8 * g2 + e;   // C/D row formula
            const size_t ob = ((size_t)b * Sn + q) * Hn + h * DHn;
            const float sc = 1.0f / acc_l[r];
#pragma unroll
            for (int dt = 0; dt < 2; ++dt)
                Out[ob + dt * 32 + l32] = o[dt][r] * sc;
        }
    }
}

extern "C" void kernel_launch(void* const* d_in, const int* in_sizes, int n_in,
                              void* d_out, int out_size, void* d_ws, size_t ws_size,
                              hipStream_t stream) {
    const float* X    = (const float*)d_in[0];
    const float* mask = (const float*)d_in[1];
    const float* Wq   = (const float*)d_in[2];
    const float* bq   = (const float*)d_in[3];
    const float* Wk   = (const float*)d_in[4];
    const float* bk   = (const float*)d_in[5];
    const float* Wv   = (const float*)d_in[6];
    const float* bv   = (const float*)d_in[7];
    float* out = (float*)d_out;

    const size_t NE = (size_t)Mn * Hn;         // 4M elements
    _Float16* Xh  = (_Float16*)d_ws;           // 8 MB
    _Float16* WT  = Xh + NE;                   // 3 x 2 MB
    _Float16* Qh  = WT + (size_t)3 * Hn * Hn;  // 8 MB
    _Float16* Kh  = Qh + NE;                   // 8 MB
    _Float16* VTh = Kh + NE;                   // 8 MB (total 38 MB)

    prep<<<dim3(4096 + 768), dim3(256), 0, stream>>>(X, Wq, Wk, Wv, Xh, WT);

    dim3 g1(Mn / 128, Hn / 128, 3), b1(256);
    qkv_mfma<<<g1, b1, 0, stream>>>(Xh, WT, bq, bk, bv, Qh, Kh, VTh);

    dim3 g2(Sn / 128, NHn, Bn), b2(256);
    attn<<<g2, b2, 0, stream>>>(Qh, Kh, VTh, mask, out);
}